// Round 1
// baseline (560.745 us; speedup 1.0000x reference)
//
#include <hip/hip_runtime.h>
#include <math.h>

#define N_NODES 4096
#define B_GR 4
#define FIN_K 354
#define HID 352
#define NHEAD 4
#define PH 88
#define E_EDGES 65536
#define ETOT (E_EDGES + N_NODES)
#define EPSV 1e-5f
#define SLOPE 0.2f
#define SPLITS 64

// ---------------- CSR build ----------------
__global__ void k_zero_int(int* p, int n) {
    int i = blockIdx.x * blockDim.x + threadIdx.x;
    if (i < n) p[i] = 0;
}

__global__ void k_hist(const int* __restrict__ ei, int* __restrict__ cnt) {
    int e = blockIdx.x * blockDim.x + threadIdx.x;
    if (e >= ETOT) return;
    int dst = (e < E_EDGES) ? ei[E_EDGES + e] : (e - E_EDGES);
    atomicAdd(&cnt[dst], 1);
}

__global__ void k_scan(const int* __restrict__ cnt, int* __restrict__ rp) {
    // one block, 256 threads, 16 counts each -> exclusive scan of 4096
    __shared__ int tot[256];
    int t = threadIdx.x;
    int base = t * 16;
    int loc[16];
    int s = 0;
    #pragma unroll
    for (int i = 0; i < 16; i++) { loc[i] = s; s += cnt[base + i]; }
    tot[t] = s;
    __syncthreads();
    for (int off = 1; off < 256; off <<= 1) {
        int v = (t >= off) ? tot[t - off] : 0;
        __syncthreads();
        tot[t] += v;
        __syncthreads();
    }
    int excl = (t == 0) ? 0 : tot[t - 1];
    #pragma unroll
    for (int i = 0; i < 16; i++) rp[base + i] = excl + loc[i];
    if (t == 255) rp[N_NODES] = tot[255];
}

__global__ void k_scatter(const int* __restrict__ ei, const int* __restrict__ rp,
                          int* __restrict__ cur, int* __restrict__ col) {
    int e = blockIdx.x * blockDim.x + threadIdx.x;
    if (e >= ETOT) return;
    int src, dst;
    if (e < E_EDGES) { src = ei[e]; dst = ei[E_EDGES + e]; }
    else { src = e - E_EDGES; dst = src; }
    int pos = rp[dst] + atomicAdd(&cur[dst], 1);
    col[pos] = src;
}

// ---------------- GEMM: C[b][m][0..351] = A[b] @ W ----------------
// ATRANS: A element (m,k) at Ab[k*M + m]  (layer 1 reads x[B][FIN][N] directly)
// else  : A element (m,k) at Ab[m*K + k]  (K must be %32==0)
template<bool ATRANS>
__global__ __launch_bounds__(256) void k_gemm(
    const float* __restrict__ A, const float* __restrict__ W,
    float* __restrict__ C, int M, int K)
{
    const int NOUT = HID;
    int b = blockIdx.z;
    int m0 = blockIdx.y * 64;
    int n0 = blockIdx.x * 64;
    const float* Ab = A + (size_t)b * (size_t)M * (size_t)K;
    float* Cb = C + (size_t)b * (size_t)M * NOUT;
    __shared__ float As[32][68];
    __shared__ float Bs[32][64];
    int tid = threadIdx.x;
    int tx = tid & 15, ty = tid >> 4;
    float acc[4][4];
    #pragma unroll
    for (int i = 0; i < 4; i++)
        #pragma unroll
        for (int j = 0; j < 4; j++) acc[i][j] = 0.f;

    for (int k0 = 0; k0 < K; k0 += 32) {
        if (ATRANS) {
            #pragma unroll
            for (int it = 0; it < 2; ++it) {
                int f = tid * 2 + it;       // 0..511
                int kk = f >> 4;            // 0..31
                int m4 = (f & 15) * 4;      // 0..60
                float4 v = make_float4(0.f, 0.f, 0.f, 0.f);
                if (k0 + kk < K)
                    v = *reinterpret_cast<const float4*>(&Ab[(size_t)(k0 + kk) * M + m0 + m4]);
                *reinterpret_cast<float4*>(&As[kk][m4]) = v;
            }
        } else {
            #pragma unroll
            for (int it = 0; it < 2; ++it) {
                int f = tid * 2 + it;
                int mm = f >> 3;            // 0..63
                int k4 = (f & 7) * 4;       // 0..28
                float4 v = *reinterpret_cast<const float4*>(&Ab[(size_t)(m0 + mm) * K + k0 + k4]);
                As[k4 + 0][mm] = v.x;
                As[k4 + 1][mm] = v.y;
                As[k4 + 2][mm] = v.z;
                As[k4 + 3][mm] = v.w;
            }
        }
        #pragma unroll
        for (int it = 0; it < 2; ++it) {
            int f = tid * 2 + it;
            int kk = f >> 4;
            int n4 = (f & 15) * 4;
            float4 v = make_float4(0.f, 0.f, 0.f, 0.f);
            if ((n0 + n4) < NOUT && (k0 + kk) < K)
                v = *reinterpret_cast<const float4*>(&W[(size_t)(k0 + kk) * NOUT + n0 + n4]);
            *reinterpret_cast<float4*>(&Bs[kk][n4]) = v;
        }
        __syncthreads();
        #pragma unroll
        for (int kk = 0; kk < 32; ++kk) {
            float4 a = *reinterpret_cast<const float4*>(&As[kk][ty * 4]);
            float4 bb = *reinterpret_cast<const float4*>(&Bs[kk][tx * 4]);
            float av[4] = {a.x, a.y, a.z, a.w};
            float bv[4] = {bb.x, bb.y, bb.z, bb.w};
            #pragma unroll
            for (int i = 0; i < 4; i++)
                #pragma unroll
                for (int j = 0; j < 4; j++)
                    acc[i][j] = fmaf(av[i], bv[j], acc[i][j]);
        }
        __syncthreads();
    }
    if (n0 + tx * 4 < NOUT) {
        #pragma unroll
        for (int i = 0; i < 4; i++) {
            float4 v = make_float4(acc[i][0], acc[i][1], acc[i][2], acc[i][3]);
            *reinterpret_cast<float4*>(&Cb[(size_t)(m0 + ty * 4 + i) * NOUT + n0 + tx * 4]) = v;
        }
    }
}

// ---------------- attention dot products ----------------
__global__ void k_att(const float* __restrict__ xh,
                      const float* __restrict__ as_, const float* __restrict__ ad_,
                      float* __restrict__ osrc, float* __restrict__ odst) {
    int idx = blockIdx.x * blockDim.x + threadIdx.x; // (b*N+n)*4 + h
    if (idx >= B_GR * N_NODES * NHEAD) return;
    int h = idx & 3;
    int bn = idx >> 2;
    const float* base = xh + (size_t)bn * HID + h * PH;
    const float* a1 = as_ + h * PH;
    const float* a2 = ad_ + h * PH;
    float s1 = 0.f, s2 = 0.f;
    #pragma unroll
    for (int c = 0; c < PH; c += 4) {
        float4 v = *reinterpret_cast<const float4*>(&base[c]);
        float4 w1 = *reinterpret_cast<const float4*>(&a1[c]);
        float4 w2 = *reinterpret_cast<const float4*>(&a2[c]);
        s1 += v.x * w1.x + v.y * w1.y + v.z * w1.z + v.w * w1.w;
        s2 += v.x * w2.x + v.y * w2.y + v.z * w2.z + v.w * w2.w;
    }
    osrc[idx] = s1;
    odst[idx] = s2;
}

// ---------------- edge softmax + aggregation ----------------
__global__ __launch_bounds__(384) void k_agg(
    const float* __restrict__ xh, const float* __restrict__ asrc,
    const float* __restrict__ adst, const int* __restrict__ rp,
    const int* __restrict__ col, const float* __restrict__ bias,
    float* __restrict__ g)
{
    int dst = blockIdx.x;
    int b = blockIdx.y;
    int t = threadIdx.x;
    int h = t & 3, slot = t >> 2; // slot 0..95
    int beg = rp[dst], end = rp[dst + 1];
    int deg = end - beg;
    const float* asB = asrc + (size_t)b * N_NODES * NHEAD;
    const float* adB = adst + (size_t)b * N_NODES * NHEAD;
    __shared__ float s_red[96][4];
    __shared__ float s_m[4], s_inv[4];
    __shared__ float s_alpha[96][4];
    __shared__ int s_src[96];
    float my_adst = adB[dst * 4 + h];

    // pass 1: per-head max of leaky_relu logits
    float lm = -1e30f;
    for (int i = slot; i < deg; i += 96) {
        int s = col[beg + i];
        float x = asB[s * 4 + h] + my_adst;
        float lg = (x > 0.f) ? x : SLOPE * x;
        lm = fmaxf(lm, lg);
    }
    s_red[slot][h] = lm;
    __syncthreads();
    float vred;
    if (t < 128) {
        int q = t >> 2;
        vred = fmaxf(fmaxf(s_red[q][h], s_red[q + 32][h]), s_red[q + 64][h]);
    }
    __syncthreads();
    if (t < 128) s_red[t >> 2][h] = vred;
    __syncthreads();
    if (t < 4) {
        float m = s_red[0][t];
        for (int q = 1; q < 32; q++) m = fmaxf(m, s_red[q][t]);
        s_m[t] = m;
    }
    __syncthreads();

    // pass 2: denominator
    float m_h = s_m[h];
    float ls = 0.f;
    for (int i = slot; i < deg; i += 96) {
        int s = col[beg + i];
        float x = asB[s * 4 + h] + my_adst;
        float lg = (x > 0.f) ? x : SLOPE * x;
        ls += expf(lg - m_h);
    }
    s_red[slot][h] = ls;
    __syncthreads();
    float vsum;
    if (t < 128) {
        int q = t >> 2;
        vsum = s_red[q][h] + s_red[q + 32][h] + s_red[q + 64][h];
    }
    __syncthreads();
    if (t < 128) s_red[t >> 2][h] = vsum;
    __syncthreads();
    if (t < 4) {
        float sden = 0.f;
        for (int q = 0; q < 32; q++) sden += s_red[q][t];
        s_inv[t] = 1.0f / sden;
    }
    __syncthreads();

    // pass 3: chunked alpha + gather-accumulate
    int c = t;
    int ch = c / PH;
    float acc = 0.f;
    const float* xb = xh + (size_t)b * N_NODES * HID;
    for (int c0 = 0; c0 < deg; c0 += 96) {
        int nthis = min(96, deg - c0);
        if (slot < nthis) {
            int s = col[beg + c0 + slot];
            if (h == 0) s_src[slot] = s;
            float x = asB[s * 4 + h] + my_adst;
            float lg = (x > 0.f) ? x : SLOPE * x;
            s_alpha[slot][h] = expf(lg - m_h) * s_inv[h];
        }
        __syncthreads();
        if (c < HID) {
            for (int i = 0; i < nthis; i++) {
                acc = fmaf(s_alpha[i][ch], xb[(size_t)s_src[i] * HID + c], acc);
            }
        }
        __syncthreads();
    }
    if (c < HID) g[((size_t)b * N_NODES + dst) * HID + c] = acc + bias[c];
}

// ---------------- GraphNorm split reduce ----------------
__global__ __launch_bounds__(384) void k_reduce(const float* __restrict__ g,
                                                float* __restrict__ ps, float* __restrict__ pss) {
    int b = blockIdx.y, chunk = blockIdx.x;
    int c = threadIdx.x;
    if (c >= HID) return;
    const int ROWS = N_NODES / SPLITS;
    int n0 = chunk * ROWS;
    const float* base = g + ((size_t)b * N_NODES + n0) * HID + c;
    float s = 0.f, ss = 0.f;
    for (int r = 0; r < ROWS; r++) {
        float v = base[(size_t)r * HID];
        s += v;
        ss = fmaf(v, v, ss);
    }
    ps[((size_t)b * SPLITS + chunk) * HID + c] = s;
    pss[((size_t)b * SPLITS + chunk) * HID + c] = ss;
}

__global__ void k_norm_final(const float* __restrict__ ps, const float* __restrict__ pss,
                             const float* __restrict__ ms, const float* __restrict__ w,
                             float* __restrict__ mu_ms, float* __restrict__ scale) {
    int b = blockIdx.x;
    int c = threadIdx.x;
    if (c >= HID) return;
    float s = 0.f, ss = 0.f;
    for (int q = 0; q < SPLITS; q++) {
        s += ps[((size_t)b * SPLITS + q) * HID + c];
        ss += pss[((size_t)b * SPLITS + q) * HID + c];
    }
    float mu = s / (float)N_NODES;
    float Eh2 = ss / (float)N_NODES;
    float msv = ms[c];
    float var = Eh2 - 2.f * msv * mu * mu + msv * msv * mu * mu;
    float rstd = 1.0f / sqrtf(var + EPSV);
    mu_ms[b * HID + c] = msv * mu;
    scale[b * HID + c] = rstd * w[c];
}

template<bool RES>
__global__ void k_apply(const float* __restrict__ g, const float* __restrict__ hprev,
                        const float* __restrict__ mu_ms, const float* __restrict__ scale,
                        const float* __restrict__ gnb, float* __restrict__ hout) {
    size_t idx = (size_t)blockIdx.x * blockDim.x + threadIdx.x;
    size_t total = (size_t)B_GR * N_NODES * HID;
    if (idx >= total) return;
    int c = (int)(idx % HID);
    int b = (int)(idx / ((size_t)N_NODES * HID));
    float v = g[idx];
    float o = (v - mu_ms[b * HID + c]) * scale[b * HID + c] + gnb[c];
    if (RES) o += hprev[idx];
    hout[idx] = fmaxf(o, 0.f);
}

// ---------------- pool + classifier ----------------
__global__ __launch_bounds__(384) void k_final(const float* __restrict__ ps,
                                               const float* __restrict__ clfw,
                                               const float* __restrict__ clfb,
                                               float* __restrict__ out) {
    int b = blockIdx.x;
    int t = threadIdx.x;
    __shared__ float buf[384];
    float v = 0.f;
    if (t < HID) {
        float s = 0.f;
        for (int q = 0; q < SPLITS; q++) s += ps[((size_t)b * SPLITS + q) * HID + t];
        v = (s / (float)N_NODES) * clfw[t];
    }
    buf[t] = v;
    __syncthreads();
    if (t < 64) {
        float acc = 0.f;
        for (int j = t; j < 384; j += 64) acc += buf[j];
        for (int off = 32; off; off >>= 1) acc += __shfl_down(acc, off);
        if (t == 0) out[b] = acc + clfb[0];
    }
}

extern "C" void kernel_launch(void* const* d_in, const int* in_sizes, int n_in,
                              void* d_out, int out_size, void* d_ws, size_t ws_size,
                              hipStream_t stream) {
    const float* x = (const float*)d_in[0];
    const int* ei = (const int*)d_in[1];
    const float* W[3]   = {(const float*)d_in[2],  (const float*)d_in[9],  (const float*)d_in[16]};
    const float* as_[3] = {(const float*)d_in[3],  (const float*)d_in[10], (const float*)d_in[17]};
    const float* ad_[3] = {(const float*)d_in[4],  (const float*)d_in[11], (const float*)d_in[18]};
    const float* bi[3]  = {(const float*)d_in[5],  (const float*)d_in[12], (const float*)d_in[19]};
    const float* gw[3]  = {(const float*)d_in[6],  (const float*)d_in[13], (const float*)d_in[20]};
    const float* gb[3]  = {(const float*)d_in[7],  (const float*)d_in[14], (const float*)d_in[21]};
    const float* gms[3] = {(const float*)d_in[8],  (const float*)d_in[15], (const float*)d_in[22]};
    const float* clfw = (const float*)d_in[23];
    const float* clfb = (const float*)d_in[24];
    float* out = (float*)d_out;

    char* ws = (char*)d_ws;
    size_t off = 0;
    auto alloc = [&](size_t bytes) -> void* {
        void* p = ws + off;
        off += (bytes + 255) & ~(size_t)255;
        return p;
    };
    size_t bigf = sizeof(float) * (size_t)B_GR * N_NODES * HID;
    float* xh    = (float*)alloc(bigf);
    float* gbuf  = (float*)alloc(bigf);
    float* hA    = (float*)alloc(bigf);
    float* hB    = (float*)alloc(bigf);
    float* a_s   = (float*)alloc(sizeof(float) * B_GR * N_NODES * NHEAD);
    float* a_d   = (float*)alloc(sizeof(float) * B_GR * N_NODES * NHEAD);
    float* ps    = (float*)alloc(sizeof(float) * B_GR * SPLITS * HID);
    float* pss   = (float*)alloc(sizeof(float) * B_GR * SPLITS * HID);
    float* mu_ms = (float*)alloc(sizeof(float) * B_GR * HID);
    float* scale = (float*)alloc(sizeof(float) * B_GR * HID);
    int* rp  = (int*)alloc(sizeof(int) * (N_NODES + 1));
    int* cnt = (int*)alloc(sizeof(int) * N_NODES);
    int* col = (int*)alloc(sizeof(int) * ETOT);

    // CSR build (topology shared across layers & graphs)
    k_zero_int<<<(N_NODES + 255) / 256, 256, 0, stream>>>(cnt, N_NODES);
    k_hist<<<(ETOT + 255) / 256, 256, 0, stream>>>(ei, cnt);
    k_scan<<<1, 256, 0, stream>>>(cnt, rp);
    k_zero_int<<<(N_NODES + 255) / 256, 256, 0, stream>>>(cnt, N_NODES);
    k_scatter<<<(ETOT + 255) / 256, 256, 0, stream>>>(ei, rp, cnt, col);

    const float* hin = nullptr;
    float* hcur = hA;
    dim3 ggrid(6, N_NODES / 64, B_GR);
    dim3 agrid(N_NODES, B_GR);
    dim3 rgrid(SPLITS, B_GR);
    size_t total = (size_t)B_GR * N_NODES * HID;
    int ablocks = (int)((total + 255) / 256);

    for (int l = 0; l < 3; l++) {
        if (l == 0) k_gemm<true><<<ggrid, 256, 0, stream>>>(x, W[0], xh, N_NODES, FIN_K);
        else        k_gemm<false><<<ggrid, 256, 0, stream>>>(hin, W[l], xh, N_NODES, HID);
        k_att<<<(B_GR * N_NODES * NHEAD + 255) / 256, 256, 0, stream>>>(xh, as_[l], ad_[l], a_s, a_d);
        k_agg<<<agrid, 384, 0, stream>>>(xh, a_s, a_d, rp, col, bi[l], gbuf);
        k_reduce<<<rgrid, 384, 0, stream>>>(gbuf, ps, pss);
        k_norm_final<<<B_GR, 384, 0, stream>>>(ps, pss, gms[l], gw[l], mu_ms, scale);
        if (l == 0) k_apply<false><<<ablocks, 256, 0, stream>>>(gbuf, nullptr, mu_ms, scale, gb[l], hcur);
        else        k_apply<true><<<ablocks, 256, 0, stream>>>(gbuf, hin, mu_ms, scale, gb[l], hcur);
        hin = hcur;
        hcur = (hcur == hA) ? hB : hA;
    }
    // global mean pool on h3 (= hin) + classifier
    k_reduce<<<rgrid, 384, 0, stream>>>(hin, ps, pss);
    k_final<<<B_GR, 384, 0, stream>>>(ps, clfw, clfb, out);
}

// Round 2
// 492.136 us; speedup vs baseline: 1.1394x; 1.1394x over previous
//
#include <hip/hip_runtime.h>
#include <math.h>

#define N_NODES 4096
#define B_GR 4
#define FIN_K 354
#define HID 352
#define NHEAD 4
#define PH 88
#define E_EDGES 65536
#define ETOT (E_EDGES + N_NODES)
#define EPSV 1e-5f
#define SLOPE 0.2f
#define SPLITS 64

// ---------------- CSR build ----------------
__global__ void k_zero_int(int* p, int n) {
    int i = blockIdx.x * blockDim.x + threadIdx.x;
    if (i < n) p[i] = 0;
}

__global__ void k_hist(const int* __restrict__ ei, int* __restrict__ cnt) {
    int e = blockIdx.x * blockDim.x + threadIdx.x;
    if (e >= ETOT) return;
    int dst = (e < E_EDGES) ? ei[E_EDGES + e] : (e - E_EDGES);
    atomicAdd(&cnt[dst], 1);
}

__global__ void k_scan(const int* __restrict__ cnt, int* __restrict__ rp) {
    __shared__ int tot[256];
    int t = threadIdx.x;
    int base = t * 16;
    int loc[16];
    int s = 0;
    #pragma unroll
    for (int i = 0; i < 16; i++) { loc[i] = s; s += cnt[base + i]; }
    tot[t] = s;
    __syncthreads();
    for (int off = 1; off < 256; off <<= 1) {
        int v = (t >= off) ? tot[t - off] : 0;
        __syncthreads();
        tot[t] += v;
        __syncthreads();
    }
    int excl = (t == 0) ? 0 : tot[t - 1];
    #pragma unroll
    for (int i = 0; i < 16; i++) rp[base + i] = excl + loc[i];
    if (t == 255) rp[N_NODES] = tot[255];
}

__global__ void k_scatter(const int* __restrict__ ei, const int* __restrict__ rp,
                          int* __restrict__ cur, int* __restrict__ col) {
    int e = blockIdx.x * blockDim.x + threadIdx.x;
    if (e >= ETOT) return;
    int src, dst;
    if (e < E_EDGES) { src = ei[e]; dst = ei[E_EDGES + e]; }
    else { src = e - E_EDGES; dst = src; }
    int pos = rp[dst] + atomicAdd(&cur[dst], 1);
    col[pos] = src;
}

// ---------------- GEMM: C[b][m][0..351] = A[b] @ W ----------------
template<bool ATRANS>
__global__ __launch_bounds__(256) void k_gemm(
    const float* __restrict__ A, const float* __restrict__ W,
    float* __restrict__ C, int M, int K)
{
    const int NOUT = HID;
    int b = blockIdx.z;
    int m0 = blockIdx.y * 64;
    int n0 = blockIdx.x * 64;
    const float* Ab = A + (size_t)b * (size_t)M * (size_t)K;
    float* Cb = C + (size_t)b * (size_t)M * NOUT;
    __shared__ float As[32][68];
    __shared__ float Bs[32][64];
    int tid = threadIdx.x;
    int tx = tid & 15, ty = tid >> 4;
    float acc[4][4];
    #pragma unroll
    for (int i = 0; i < 4; i++)
        #pragma unroll
        for (int j = 0; j < 4; j++) acc[i][j] = 0.f;

    for (int k0 = 0; k0 < K; k0 += 32) {
        if (ATRANS) {
            #pragma unroll
            for (int it = 0; it < 2; ++it) {
                int f = tid * 2 + it;
                int kk = f >> 4;
                int m4 = (f & 15) * 4;
                float4 v = make_float4(0.f, 0.f, 0.f, 0.f);
                if (k0 + kk < K)
                    v = *reinterpret_cast<const float4*>(&Ab[(size_t)(k0 + kk) * M + m0 + m4]);
                *reinterpret_cast<float4*>(&As[kk][m4]) = v;
            }
        } else {
            #pragma unroll
            for (int it = 0; it < 2; ++it) {
                int f = tid * 2 + it;
                int mm = f >> 3;
                int k4 = (f & 7) * 4;
                float4 v = *reinterpret_cast<const float4*>(&Ab[(size_t)(m0 + mm) * K + k0 + k4]);
                As[k4 + 0][mm] = v.x;
                As[k4 + 1][mm] = v.y;
                As[k4 + 2][mm] = v.z;
                As[k4 + 3][mm] = v.w;
            }
        }
        #pragma unroll
        for (int it = 0; it < 2; ++it) {
            int f = tid * 2 + it;
            int kk = f >> 4;
            int n4 = (f & 15) * 4;
            float4 v = make_float4(0.f, 0.f, 0.f, 0.f);
            if ((n0 + n4) < NOUT && (k0 + kk) < K)
                v = *reinterpret_cast<const float4*>(&W[(size_t)(k0 + kk) * NOUT + n0 + n4]);
            *reinterpret_cast<float4*>(&Bs[kk][n4]) = v;
        }
        __syncthreads();
        #pragma unroll
        for (int kk = 0; kk < 32; ++kk) {
            float4 a = *reinterpret_cast<const float4*>(&As[kk][ty * 4]);
            float4 bb = *reinterpret_cast<const float4*>(&Bs[kk][tx * 4]);
            float av[4] = {a.x, a.y, a.z, a.w};
            float bv[4] = {bb.x, bb.y, bb.z, bb.w};
            #pragma unroll
            for (int i = 0; i < 4; i++)
                #pragma unroll
                for (int j = 0; j < 4; j++)
                    acc[i][j] = fmaf(av[i], bv[j], acc[i][j]);
        }
        __syncthreads();
    }
    if (n0 + tx * 4 < NOUT) {
        #pragma unroll
        for (int i = 0; i < 4; i++) {
            float4 v = make_float4(acc[i][0], acc[i][1], acc[i][2], acc[i][3]);
            *reinterpret_cast<float4*>(&Cb[(size_t)(m0 + ty * 4 + i) * NOUT + n0 + tx * 4]) = v;
        }
    }
}

// ---------------- attention dot products ----------------
// writes interleaved layout [n][b][h]: one 64B line per node covers all 16 logit scalars
__global__ void k_att(const float* __restrict__ xh,
                      const float* __restrict__ as_, const float* __restrict__ ad_,
                      float* __restrict__ osrc, float* __restrict__ odst) {
    int idx = blockIdx.x * blockDim.x + threadIdx.x; // (b*N+n)*4 + h
    if (idx >= B_GR * N_NODES * NHEAD) return;
    int h = idx & 3;
    int bn = idx >> 2;
    int b = bn / N_NODES;
    int n = bn - b * N_NODES;
    const float* base = xh + (size_t)bn * HID + h * PH;
    const float* a1 = as_ + h * PH;
    const float* a2 = ad_ + h * PH;
    float s1 = 0.f, s2 = 0.f;
    #pragma unroll
    for (int c = 0; c < PH; c += 4) {
        float4 v = *reinterpret_cast<const float4*>(&base[c]);
        float4 w1 = *reinterpret_cast<const float4*>(&a1[c]);
        float4 w2 = *reinterpret_cast<const float4*>(&a2[c]);
        s1 += v.x * w1.x + v.y * w1.y + v.z * w1.z + v.w * w1.w;
        s2 += v.x * w2.x + v.y * w2.y + v.z * w2.z + v.w * w2.w;
    }
    int oidx = n * 16 + b * 4 + h;
    osrc[oidx] = s1;
    odst[oidx] = s2;
}

// ---------------- edge softmax + aggregation, all 4 graphs per block ----------------
__global__ __launch_bounds__(384) void k_agg(
    const float* __restrict__ xh, const float* __restrict__ asrc,
    const float* __restrict__ adst, const int* __restrict__ rp,
    const int* __restrict__ col, const float* __restrict__ bias,
    float* __restrict__ g)
{
    int dst = blockIdx.x;
    int t = threadIdx.x;
    int gh = t & 15;     // b*4+h
    int slot = t >> 4;   // 0..23
    int beg = rp[dst], end = rp[dst + 1];
    int deg = end - beg;
    __shared__ float s_red[24][16];
    __shared__ float s_m[16], s_inv[16];
    __shared__ float s_alpha[24][16];
    __shared__ int s_src[24];
    float my_adst = adst[dst * 16 + gh];

    // pass 1: per-(graph,head) max of leaky_relu logits
    float lm = -1e30f;
    for (int i = slot; i < deg; i += 24) {
        int s = col[beg + i];
        float x = asrc[s * 16 + gh] + my_adst;
        float lg = (x > 0.f) ? x : SLOPE * x;
        lm = fmaxf(lm, lg);
    }
    s_red[slot][gh] = lm;
    __syncthreads();
    if (t < 16) {
        float m = s_red[0][t];
        #pragma unroll
        for (int q = 1; q < 24; q++) m = fmaxf(m, s_red[q][t]);
        s_m[t] = m;
    }
    __syncthreads();
    float m_h = s_m[gh];

    // pass 2: denominator
    float ls = 0.f;
    for (int i = slot; i < deg; i += 24) {
        int s = col[beg + i];
        float x = asrc[s * 16 + gh] + my_adst;
        float lg = (x > 0.f) ? x : SLOPE * x;
        ls += expf(lg - m_h);
    }
    s_red[slot][gh] = ls;
    __syncthreads();
    if (t < 16) {
        float sden = 0.f;
        #pragma unroll
        for (int q = 0; q < 24; q++) sden += s_red[q][t];
        s_inv[t] = 1.0f / sden;
    }
    __syncthreads();

    // pass 3: chunked alpha + gather-accumulate, 4 graphs per thread
    int c = t;               // channel 0..351 (352..383 only help with alpha)
    int ch = (c < HID) ? (c / PH) : 0;
    float acc0 = 0.f, acc1 = 0.f, acc2 = 0.f, acc3 = 0.f;
    const float* xb0 = xh;
    const float* xb1 = xh + (size_t)1 * N_NODES * HID;
    const float* xb2 = xh + (size_t)2 * N_NODES * HID;
    const float* xb3 = xh + (size_t)3 * N_NODES * HID;
    for (int c0 = 0; c0 < deg; c0 += 24) {
        int nthis = min(24, deg - c0);
        if (slot < nthis) {
            int s = col[beg + c0 + slot];
            if (gh == 0) s_src[slot] = s;
            float x = asrc[s * 16 + gh] + my_adst;
            float lg = (x > 0.f) ? x : SLOPE * x;
            s_alpha[slot][gh] = expf(lg - m_h) * s_inv[gh];
        }
        __syncthreads();
        if (c < HID) {
            #pragma unroll 2
            for (int i = 0; i < nthis; i++) {
                int s = s_src[i];
                size_t rowoff = (size_t)s * HID + c;
                float v0 = xb0[rowoff];
                float v1 = xb1[rowoff];
                float v2 = xb2[rowoff];
                float v3 = xb3[rowoff];
                acc0 = fmaf(s_alpha[i][0 * 4 + ch], v0, acc0);
                acc1 = fmaf(s_alpha[i][1 * 4 + ch], v1, acc1);
                acc2 = fmaf(s_alpha[i][2 * 4 + ch], v2, acc2);
                acc3 = fmaf(s_alpha[i][3 * 4 + ch], v3, acc3);
            }
        }
        __syncthreads();
    }
    if (c < HID) {
        float bv = bias[c];
        g[((size_t)0 * N_NODES + dst) * HID + c] = acc0 + bv;
        g[((size_t)1 * N_NODES + dst) * HID + c] = acc1 + bv;
        g[((size_t)2 * N_NODES + dst) * HID + c] = acc2 + bv;
        g[((size_t)3 * N_NODES + dst) * HID + c] = acc3 + bv;
    }
}

// ---------------- GraphNorm split reduce ----------------
__global__ __launch_bounds__(384) void k_reduce(const float* __restrict__ g,
                                                float* __restrict__ ps, float* __restrict__ pss) {
    int b = blockIdx.y, chunk = blockIdx.x;
    int c = threadIdx.x;
    if (c >= HID) return;
    const int ROWS = N_NODES / SPLITS;
    int n0 = chunk * ROWS;
    const float* base = g + ((size_t)b * N_NODES + n0) * HID + c;
    float s = 0.f, ss = 0.f;
    for (int r = 0; r < ROWS; r++) {
        float v = base[(size_t)r * HID];
        s += v;
        ss = fmaf(v, v, ss);
    }
    ps[((size_t)b * SPLITS + chunk) * HID + c] = s;
    pss[((size_t)b * SPLITS + chunk) * HID + c] = ss;
}

__global__ void k_norm_final(const float* __restrict__ ps, const float* __restrict__ pss,
                             const float* __restrict__ ms, const float* __restrict__ w,
                             float* __restrict__ mu_ms, float* __restrict__ scale) {
    int b = blockIdx.x;
    int c = threadIdx.x;
    if (c >= HID) return;
    float s = 0.f, ss = 0.f;
    for (int q = 0; q < SPLITS; q++) {
        s += ps[((size_t)b * SPLITS + q) * HID + c];
        ss += pss[((size_t)b * SPLITS + q) * HID + c];
    }
    float mu = s / (float)N_NODES;
    float Eh2 = ss / (float)N_NODES;
    float msv = ms[c];
    float var = Eh2 - 2.f * msv * mu * mu + msv * msv * mu * mu;
    float rstd = 1.0f / sqrtf(var + EPSV);
    mu_ms[b * HID + c] = msv * mu;
    scale[b * HID + c] = rstd * w[c];
}

template<bool RES>
__global__ void k_apply(const float* __restrict__ g, const float* __restrict__ hprev,
                        const float* __restrict__ mu_ms, const float* __restrict__ scale,
                        const float* __restrict__ gnb, float* __restrict__ hout) {
    size_t idx = (size_t)blockIdx.x * blockDim.x + threadIdx.x;
    size_t total = (size_t)B_GR * N_NODES * HID;
    if (idx >= total) return;
    int c = (int)(idx % HID);
    int b = (int)(idx / ((size_t)N_NODES * HID));
    float v = g[idx];
    float o = (v - mu_ms[b * HID + c]) * scale[b * HID + c] + gnb[c];
    if (RES) o += hprev[idx];
    hout[idx] = fmaxf(o, 0.f);
}

// ---------------- pool + classifier ----------------
__global__ __launch_bounds__(384) void k_final(const float* __restrict__ ps,
                                               const float* __restrict__ clfw,
                                               const float* __restrict__ clfb,
                                               float* __restrict__ out) {
    int b = blockIdx.x;
    int t = threadIdx.x;
    __shared__ float buf[384];
    float v = 0.f;
    if (t < HID) {
        float s = 0.f;
        for (int q = 0; q < SPLITS; q++) s += ps[((size_t)b * SPLITS + q) * HID + t];
        v = (s / (float)N_NODES) * clfw[t];
    }
    buf[t] = v;
    __syncthreads();
    if (t < 64) {
        float acc = 0.f;
        for (int j = t; j < 384; j += 64) acc += buf[j];
        for (int off = 32; off; off >>= 1) acc += __shfl_down(acc, off);
        if (t == 0) out[b] = acc + clfb[0];
    }
}

extern "C" void kernel_launch(void* const* d_in, const int* in_sizes, int n_in,
                              void* d_out, int out_size, void* d_ws, size_t ws_size,
                              hipStream_t stream) {
    const float* x = (const float*)d_in[0];
    const int* ei = (const int*)d_in[1];
    const float* W[3]   = {(const float*)d_in[2],  (const float*)d_in[9],  (const float*)d_in[16]};
    const float* as_[3] = {(const float*)d_in[3],  (const float*)d_in[10], (const float*)d_in[17]};
    const float* ad_[3] = {(const float*)d_in[4],  (const float*)d_in[11], (const float*)d_in[18]};
    const float* bi[3]  = {(const float*)d_in[5],  (const float*)d_in[12], (const float*)d_in[19]};
    const float* gw[3]  = {(const float*)d_in[6],  (const float*)d_in[13], (const float*)d_in[20]};
    const float* gb[3]  = {(const float*)d_in[7],  (const float*)d_in[14], (const float*)d_in[21]};
    const float* gms[3] = {(const float*)d_in[8],  (const float*)d_in[15], (const float*)d_in[22]};
    const float* clfw = (const float*)d_in[23];
    const float* clfb = (const float*)d_in[24];
    float* out = (float*)d_out;

    char* ws = (char*)d_ws;
    size_t off = 0;
    auto alloc = [&](size_t bytes) -> void* {
        void* p = ws + off;
        off += (bytes + 255) & ~(size_t)255;
        return p;
    };
    size_t bigf = sizeof(float) * (size_t)B_GR * N_NODES * HID;
    float* xh    = (float*)alloc(bigf);
    float* gbuf  = (float*)alloc(bigf);
    float* hA    = (float*)alloc(bigf);
    float* hB    = (float*)alloc(bigf);
    float* a_s   = (float*)alloc(sizeof(float) * B_GR * N_NODES * NHEAD);
    float* a_d   = (float*)alloc(sizeof(float) * B_GR * N_NODES * NHEAD);
    float* ps    = (float*)alloc(sizeof(float) * B_GR * SPLITS * HID);
    float* pss   = (float*)alloc(sizeof(float) * B_GR * SPLITS * HID);
    float* mu_ms = (float*)alloc(sizeof(float) * B_GR * HID);
    float* scale = (float*)alloc(sizeof(float) * B_GR * HID);
    int* rp  = (int*)alloc(sizeof(int) * (N_NODES + 1));
    int* cnt = (int*)alloc(sizeof(int) * N_NODES);
    int* col = (int*)alloc(sizeof(int) * ETOT);

    k_zero_int<<<(N_NODES + 255) / 256, 256, 0, stream>>>(cnt, N_NODES);
    k_hist<<<(ETOT + 255) / 256, 256, 0, stream>>>(ei, cnt);
    k_scan<<<1, 256, 0, stream>>>(cnt, rp);
    k_zero_int<<<(N_NODES + 255) / 256, 256, 0, stream>>>(cnt, N_NODES);
    k_scatter<<<(ETOT + 255) / 256, 256, 0, stream>>>(ei, rp, cnt, col);

    const float* hin = nullptr;
    float* hcur = hA;
    dim3 ggrid(6, N_NODES / 64, B_GR);
    dim3 rgrid(SPLITS, B_GR);
    size_t total = (size_t)B_GR * N_NODES * HID;
    int ablocks = (int)((total + 255) / 256);

    for (int l = 0; l < 3; l++) {
        if (l == 0) k_gemm<true><<<ggrid, 256, 0, stream>>>(x, W[0], xh, N_NODES, FIN_K);
        else        k_gemm<false><<<ggrid, 256, 0, stream>>>(hin, W[l], xh, N_NODES, HID);
        k_att<<<(B_GR * N_NODES * NHEAD + 255) / 256, 256, 0, stream>>>(xh, as_[l], ad_[l], a_s, a_d);
        k_agg<<<N_NODES, 384, 0, stream>>>(xh, a_s, a_d, rp, col, bi[l], gbuf);
        k_reduce<<<rgrid, 384, 0, stream>>>(gbuf, ps, pss);
        k_norm_final<<<B_GR, 384, 0, stream>>>(ps, pss, gms[l], gw[l], mu_ms, scale);
        if (l == 0) k_apply<false><<<ablocks, 256, 0, stream>>>(gbuf, nullptr, mu_ms, scale, gb[l], hcur);
        else        k_apply<true><<<ablocks, 256, 0, stream>>>(gbuf, hin, mu_ms, scale, gb[l], hcur);
        hin = hcur;
        hcur = (hcur == hA) ? hB : hA;
    }
    k_reduce<<<rgrid, 384, 0, stream>>>(hin, ps, pss);
    k_final<<<B_GR, 384, 0, stream>>>(ps, clfw, clfb, out);
}